// Round 8
// baseline (1123.443 us; speedup 1.0000x reference)
//
#include <hip/hip_runtime.h>
#include <hip/hip_bf16.h>

#define BATCH 1024
#define N_STEPS 3
#define GAMMA_C 1.3f
#define BN_EPS_C 1e-5f
#define SQRT_HALF_C 0.70710678118654752440f
#define NBLK 256

// ---- input loader: f32 or bf16 decided at runtime by detector flag --------
__device__ __forceinline__ float ldin(const void* p, size_t i, int isbf){
  if (isbf) return __bfloat162float(((const __hip_bfloat16*)p)[i]);
  return ((const float*)p)[i];
}
__device__ __forceinline__ float4 ld4(const void* p, size_t i, int isbf){
  if (!isbf) return *(const float4*)((const float*)p + i);
  const __hip_bfloat16* q = (const __hip_bfloat16*)p + i;
  return make_float4(__bfloat162float(q[0]), __bfloat162float(q[1]),
                     __bfloat162float(q[2]), __bfloat162float(q[3]));
}

// ---- wave (64-lane) butterfly reductions ----------------------------------
__device__ __forceinline__ float wsum(float v){
#pragma unroll
  for (int o = 32; o > 0; o >>= 1) v += __shfl_xor(v, o);
  return v;
}
__device__ __forceinline__ float wmaxr(float v){
#pragma unroll
  for (int o = 32; o > 0; o >>= 1) v = fmaxf(v, __shfl_xor(v, o));
  return v;
}
__device__ __forceinline__ float wminr(float v){
#pragma unroll
  for (int o = 32; o > 0; o >>= 1) v = fminf(v, __shfl_xor(v, o));
  return v;
}

// ---- shared-memory union (max member 8.7 KB) ------------------------------
struct SmGemm { float As[32][34]; float Ws[32][34]; };
struct SmAttn { float qs[256], ks[256], vs[256], ms[256], rz[256]; float r1[4], r2[4]; };
struct SmSp   { float tabs[4][256]; unsigned int msk[4][2]; };
struct SmGst  { float ps[8][32], pss[8][32]; };
struct SmRed  { float sb[256]; };
union Smem { SmGemm g; SmAttn a; SmSp s; SmGst t; SmRed r; };

__device__ __forceinline__ float block_sum(float v, float* sb){
  int t = threadIdx.x;
  sb[t] = v; __syncthreads();
#pragma unroll
  for (int s = 128; s > 0; s >>= 1){
    if (t < s) sb[t] += sb[t + s];
    __syncthreads();
  }
  float r = sb[0]; __syncthreads();
  return r;
}

// ---- device-scope sense-reversing grid barrier ----------------------------
// bar[0] = arrival counter, bar[1] = generation. All blocks co-resident
// (256 blocks on 256 CUs). Release/acquire via __threadfence (agent-scope
// L2 writeback+invalidate on CDNA), arrival via device-scope atomics.
__device__ __forceinline__ void gbar(unsigned* bar){
  __syncthreads();
  if (threadIdx.x == 0){
    __threadfence();
    unsigned g = atomicAdd(&bar[1], 0u);
    if (atomicAdd(&bar[0], 1u) == NBLK - 1u){
      atomicExch(&bar[0], 0u);
      __threadfence();
      atomicAdd(&bar[1], 1u);
    } else {
      while (atomicAdd(&bar[1], 0u) == g){ __builtin_amdgcn_s_sleep(2); }
    }
    __threadfence();
  }
  __syncthreads();
}

// ---- GEMM tile body: C(32x32 tile) = A(32xK) @ W^T via LDS staging --------
template<typename FA, typename FW>
__device__ __forceinline__ void gemm_body(FA&& lda, FW&& ldw, int nc, SmGemm& g,
                                          int t, int n0, int m0, float* C){
  const int tx = t & 15, ty = t >> 4;
  const int lr = t >> 3, lk = (t & 7) * 4;
  float a00 = 0.f, a01 = 0.f, a10 = 0.f, a11 = 0.f;
  float4 ra = lda(0, lr, lk), rw = ldw(0, lr, lk);
  for (int c2 = 0; c2 < nc; ++c2){
    g.As[lk+0][lr] = ra.x; g.As[lk+1][lr] = ra.y; g.As[lk+2][lr] = ra.z; g.As[lk+3][lr] = ra.w;
    g.Ws[lk+0][lr] = rw.x; g.Ws[lk+1][lr] = rw.y; g.Ws[lk+2][lr] = rw.z; g.Ws[lk+3][lr] = rw.w;
    __syncthreads();
    float4 na = ra, nw = rw;
    if (c2 + 1 < nc){ na = lda((c2+1) << 5, lr, lk); nw = ldw((c2+1) << 5, lr, lk); }
#pragma unroll
    for (int kk = 0; kk < 32; ++kk){
      float2 av = *(const float2*)&g.As[kk][ty*2];
      float2 wv = *(const float2*)&g.Ws[kk][tx*2];
      a00 += av.x * wv.x; a01 += av.x * wv.y;
      a10 += av.y * wv.x; a11 += av.y * wv.y;
    }
    __syncthreads();
    ra = na; rw = nw;
  }
  int r0 = m0 + ty*2, c0 = n0 + tx*2;
  float* Cp = C + (size_t)r0 * 256 + c0;
  Cp[0] = a00; Cp[1] = a01; Cp[256] = a10; Cp[257] = a11;
}

// ---- ghost-BN stats -> per-(group,col) affine (64 active blocks) ----------
__device__ __forceinline__ void gstats_body(SmGst& G, const float* H, const void* w,
    const void* b, size_t off, float* sa, float* sb, int isbf, int bid, int t){
  int c0 = (bid & 7) * 32, g = bid >> 3;
  int tx = t & 31, q = t >> 5;
  const float* Hp = H + ((size_t)g*128 + q*16) * 256 + c0 + tx;
  float s = 0.f, ss = 0.f;
#pragma unroll
  for (int i = 0; i < 16; ++i){ float v = Hp[(size_t)i*256]; s += v; ss += v*v; }
  G.ps[q][tx] = s; G.pss[q][tx] = ss;
  __syncthreads();
  if (t < 32){
    int col = c0 + t;
    float S = 0.f, SS = 0.f;
#pragma unroll
    for (int qq = 0; qq < 8; ++qq){ S += G.ps[qq][t]; SS += G.pss[qq][t]; }
    float m = S * (1.f/128), is = rsqrtf(SS * (1.f/128) - m*m + BN_EPS_C);
    float wv = ldin(w, off + col, isbf), bv = ldin(b, off + col, isbf);
    float A = is * wv;
    sa[g*256 + col] = A;
    sb[g*256 + col] = bv - m * A;
  }
  __syncthreads();
}

// ---- scalar FT combine value for output column j (j in 0..127) ------------
__device__ __forceinline__ float combine_scalar(const float* H1, const float* H2,
    const float* sa0, const float* sb0, const float* sa1, const float* sb1, int r, int j){
  int g = r >> 7;
  float h0 = H1[(size_t)r*256 + j], h1 = H1[(size_t)r*256 + j + 128];
  float u0 = h0 * sa0[g*256 + j]     + sb0[g*256 + j];
  float u1 = h1 * sa0[g*256 + j+128] + sb0[g*256 + j+128];
  float g0 = u0 / (1.f + __expf(-u1));
  float v0 = H2[(size_t)r*256 + j]     * sa1[g*256 + j]     + sb1[g*256 + j];
  float v1 = H2[(size_t)r*256 + j+128] * sa1[g*256 + j+128] + sb1[g*256 + j+128];
  float g1 = v0 / (1.f + __expf(-v1));
  return (g0 + g1) * SQRT_HALF_C;
}

struct KParams {
  const void *x, *bemv, *gmat, *bn_w, *bn_b;
  const void *ifc0, *ibnw0, *ibnb0, *ifc1, *ibnw1, *ibnb1;
  const void *sfc0, *sbnw0, *sbnb0, *sfc1, *sbnw1, *sbnb1;
  const void *afc, *abnw, *abnb;
  const void *siw, *sib, *sow, *sob;
  float* out; float* ws;
};

__global__ void initbar_k(float* ws){
  unsigned* bar = (unsigned*)(ws + 3584);
  bar[0] = 0u; bar[1] = 0u;
}

__global__ __launch_bounds__(256)
void mega_k(KParams P){
  const int bid = blockIdx.x, t = threadIdx.x;
  __shared__ Smem sm;

  float* ws    = P.ws;
  float* xnA   = ws;                 // 256
  float* xnB   = ws + 256;           // 256
  float* lrow  = ws + 512;           // 3072
  unsigned* bar = (unsigned*)(ws + 3584);
  float* sa0   = ws + 4096;          // 2048
  float* sb0   = sa0 + 2048;
  float* sa1   = sb0 + 2048;
  float* sb1   = sa1 + 2048;
  float* saA   = sb1 + 2048;
  float* sbA   = saA + 2048;         // -> 16384
  float* xn    = ws + 16384;         // 262144
  float* H1    = xn   + 262144;
  float* H2    = H1   + 262144;
  float* Ha    = H2   + 262144;
  float* xm    = Ha   + 262144;
  float* prior = xm   + 262144;
  float* y     = prior + 262144;
  float* amaps = P.out + 196609;     // 3*1024*64 steps + 1 mloss, then amaps

  // ---- dtype detect (block-local, redundant per block) --------------------
  {
    int c = 0;
    const unsigned short* u = (const unsigned short*)P.x;
    for (int j = 0; j < 16; ++j){
      unsigned short v = u[(size_t)(t * 16 + j) * 2];
      int e = (v >> 7) & 0xFF;
      c += (e >= 118 && e <= 134);
    }
    float cf = block_sum((float)c, sm.r.sb);
    sm.r.sb[0] = cf; __syncthreads();
  }
  const int isbf = sm.r.sb[0] > 2048.f;
  __syncthreads();

  // ---- P1: full-batch BN stats -> per-feature affine ----------------------
  {
    int f = bid;  // 256 blocks, 256 features
    float s = 0.f, ss = 0.f;
    for (int r = t; r < BATCH; r += 256){
      float v = ldin(P.x, (size_t)r*256 + f, isbf);
      s += v; ss += v*v;
    }
    s  = block_sum(s, sm.r.sb);
    ss = block_sum(ss, sm.r.sb);
    if (t == 0){
      float m = s * (1.f/BATCH);
      float is = rsqrtf(ss * (1.f/BATCH) - m*m + BN_EPS_C);
      float A = is * ldin(P.bn_w, f, isbf);
      xnA[f] = A;
      xnB[f] = ldin(P.bn_b, f, isbf) - m * A;
    }
  }
  gbar(bar);

  // ---- P2: init GEMM K=512 (inline xn affine) + xn buffer write -----------
  {
    const int n0 = (bid & 7) * 32, m0 = (bid >> 3) * 32;
    auto lda = [&](int k0, int lr, int lk) -> float4 {
      int gk = k0 + lk, gr = m0 + lr;
      if (gk < 256){
        float4 xv = ld4(P.x, (size_t)gr*256 + gk, isbf);
        float4 A4 = *(const float4*)(xnA + gk);
        float4 B4 = *(const float4*)(xnB + gk);
        return make_float4(xv.x*A4.x+B4.x, xv.y*A4.y+B4.y, xv.z*A4.z+B4.z, xv.w*A4.w+B4.w);
      }
      return ld4(P.bemv, (size_t)gr*256 + (gk - 256), isbf);
    };
    auto ldw = [&](int k0, int lr, int lk) -> float4 {
      return ld4(P.ifc0, (size_t)(n0 + lr)*512 + k0 + lk, isbf);
    };
    gemm_body(lda, ldw, 16, sm.g, t, n0, m0, H1);
    // xn buffer (1 float4 per thread)
    int fi = (bid * 256 + t) * 4;
    int col = fi & 255;
    float4 xv = ld4(P.x, fi, isbf);
    float4 A4 = *(const float4*)(xnA + col);
    float4 B4 = *(const float4*)(xnB + col);
    *(float4*)(xn + fi) = make_float4(xv.x*A4.x+B4.x, xv.y*A4.y+B4.y, xv.z*A4.z+B4.z, xv.w*A4.w+B4.w);
  }
  gbar(bar);

  // ---- P3: gstats on H1 ---------------------------------------------------
  if (bid < 64) gstats_body(sm.t, H1, P.ibnw0, P.ibnb0, 0, sa0, sb0, isbf, bid, t);
  gbar(bar);

  // ---- P4: GLU-fused GEMM K=128 -> H2 -------------------------------------
  {
    const int n0 = (bid & 7) * 32, m0 = (bid >> 3) * 32;
    auto lda = [&](int k0, int lr, int lk) -> float4 {
      int gk = k0 + lk, gr = m0 + lr, g = gr >> 7;
      const float* h = H1 + (size_t)gr*256;
      float4 h0 = *(const float4*)(h + gk);
      float4 h1 = *(const float4*)(h + gk + 128);
      float4 A0 = *(const float4*)(sa0 + g*256 + gk);
      float4 B0 = *(const float4*)(sb0 + g*256 + gk);
      float4 A1 = *(const float4*)(sa0 + g*256 + gk + 128);
      float4 B1 = *(const float4*)(sb0 + g*256 + gk + 128);
      float4 r;
      r.x = (h0.x*A0.x+B0.x) / (1.f + __expf(-(h1.x*A1.x+B1.x)));
      r.y = (h0.y*A0.y+B0.y) / (1.f + __expf(-(h1.y*A1.y+B1.y)));
      r.z = (h0.z*A0.z+B0.z) / (1.f + __expf(-(h1.z*A1.z+B1.z)));
      r.w = (h0.w*A0.w+B0.w) / (1.f + __expf(-(h1.w*A1.w+B1.w)));
      return r;
    };
    auto ldw = [&](int k0, int lr, int lk) -> float4 {
      return ld4(P.ifc1, (size_t)(n0 + lr)*128 + k0 + lk, isbf);
    };
    gemm_body(lda, ldw, 4, sm.g, t, n0, m0, H2);
  }
  gbar(bar);

  // ---- P5: gstats on H2 ---------------------------------------------------
  if (bid < 64) gstats_body(sm.t, H2, P.ibnw1, P.ibnb1, 0, sa1, sb1, isbf, bid, t);
  gbar(bar);

  for (int s = 0; s < N_STEPS; ++s){
    // ---- A: GEMM K=64 with inline att-combine A-load -> Ha; steps_out[s-1]
    {
      const int n0 = (bid & 7) * 32, m0 = (bid >> 3) * 32;
      auto lda = [&](int k0, int lr, int lk) -> float4 {
        int gk = k0 + lk, gr = m0 + lr, g = gr >> 7;
        const float* h1p = H1 + (size_t)gr*256;
        const float* h2p = H2 + (size_t)gr*256;
        float4 a0 = *(const float4*)(h1p + gk + 64);
        float4 a1 = *(const float4*)(h1p + gk + 192);
        float4 c0 = *(const float4*)(sa0 + g*256 + gk + 64);
        float4 d0 = *(const float4*)(sb0 + g*256 + gk + 64);
        float4 c1 = *(const float4*)(sa0 + g*256 + gk + 192);
        float4 d1 = *(const float4*)(sb0 + g*256 + gk + 192);
        float4 b0 = *(const float4*)(h2p + gk + 64);
        float4 b1 = *(const float4*)(h2p + gk + 192);
        float4 e0 = *(const float4*)(sa1 + g*256 + gk + 64);
        float4 f0 = *(const float4*)(sb1 + g*256 + gk + 64);
        float4 e1 = *(const float4*)(sa1 + g*256 + gk + 192);
        float4 f1 = *(const float4*)(sb1 + g*256 + gk + 192);
        float4 r;
        r.x = ((a0.x*c0.x+d0.x)/(1.f+__expf(-(a1.x*c1.x+d1.x)))
             + (b0.x*e0.x+f0.x)/(1.f+__expf(-(b1.x*e1.x+f1.x)))) * SQRT_HALF_C;
        r.y = ((a0.y*c0.y+d0.y)/(1.f+__expf(-(a1.y*c1.y+d1.y)))
             + (b0.y*e0.y+f0.y)/(1.f+__expf(-(b1.y*e1.y+f1.y)))) * SQRT_HALF_C;
        r.z = ((a0.z*c0.z+d0.z)/(1.f+__expf(-(a1.z*c1.z+d1.z)))
             + (b0.z*e0.z+f0.z)/(1.f+__expf(-(b1.z*e1.z+f1.z)))) * SQRT_HALF_C;
        r.w = ((a0.w*c0.w+d0.w)/(1.f+__expf(-(a1.w*c1.w+d1.w)))
             + (b0.w*e0.w+f0.w)/(1.f+__expf(-(b1.w*e1.w+f1.w)))) * SQRT_HALF_C;
        return r;
      };
      auto ldw = [&](int k0, int lr, int lk) -> float4 {
        return ld4(P.afc, (size_t)s*16384 + (size_t)(n0 + lr)*64 + k0 + lk, isbf);
      };
      gemm_body(lda, ldw, 2, sm.g, t, n0, m0, Ha);
      if (s > 0){
        int idx = bid * 256 + t;
        int r = idx >> 6, j = idx & 63;
        float f = combine_scalar(H1, H2, sa0, sb0, sa1, sb1, r, j);
        P.out[(size_t)(s-1)*65536 + idx] = f > 0.f ? f : 0.01f*f;
      }
    }
    gbar(bar);

    // ---- B: gstats on Ha ---------------------------------------------------
    if (bid < 64) gstats_body(sm.t, Ha, P.abnw, P.abnb, (size_t)s*256, saA, sbA, isbf, bid, t);
    gbar(bar);

    // ---- C: sparsemax + prior + loss + sparse xm GEMM ----------------------
    {
      int lane = t & 63, wv = t >> 6;
      int b0 = bid * 4;
      int b = b0 + wv, g = b >> 7;
      size_t rb = (size_t)b * 256;
      int j0 = lane * 4;
      float4 h4 = *(const float4*)(Ha + rb + j0);
      float4 A4 = *(const float4*)(saA + (size_t)g*256 + j0);
      float4 B4 = *(const float4*)(sbA + (size_t)g*256 + j0);
      float pr[4];
      if (s == 0){ pr[0] = pr[1] = pr[2] = pr[3] = 1.f; }
      else { float4 p4 = *(const float4*)(prior + rb + j0); pr[0]=p4.x; pr[1]=p4.y; pr[2]=p4.z; pr[3]=p4.w; }
      float z[4];
      z[0] = (h4.x*A4.x + B4.x) * pr[0];
      z[1] = (h4.y*A4.y + B4.y) * pr[1];
      z[2] = (h4.z*A4.z + B4.z) * pr[2];
      z[3] = (h4.w*A4.w + B4.w) * pr[3];
      float zm = wmaxr(fmaxf(fmaxf(z[0], z[1]), fmaxf(z[2], z[3])));
      float lo = zm - 1.f, hi = zm;
#pragma unroll 1
      for (int it = 0; it < 30; ++it){
        float mid = 0.5f * (lo + hi);
        float sv = 0.f;
#pragma unroll
        for (int e = 0; e < 4; ++e){ float d = z[e] - mid; sv += d > 0.f ? d : 0.f; }
        sv = wsum(sv);
        if (sv >= 1.f) lo = mid; else hi = mid;
      }
      float tau = 0.5f * (lo + hi);
      float p[4], ls = 0.f;
#pragma unroll
      for (int e = 0; e < 4; ++e){
        p[e] = z[e] - tau; p[e] = p[e] > 0.f ? p[e] : 0.f;
        ls += p[e] * __logf(p[e] + 1e-15f);
      }
      *(float4*)&sm.s.tabs[wv][j0] = make_float4(p[0], p[1], p[2], p[3]);
      *(float4*)(prior + rb + j0) = make_float4(pr[0]*(GAMMA_C-p[0]), pr[1]*(GAMMA_C-p[1]),
                                                pr[2]*(GAMMA_C-p[2]), pr[3]*(GAMMA_C-p[3]));
      ls = wsum(ls);
      if (lane == 0) lrow[s*1024 + b] = ls;
      bool nz = (p[0] > 0.f) | (p[1] > 0.f) | (p[2] > 0.f) | (p[3] > 0.f);
      unsigned long long bm = __ballot(nz);
      if (lane == 0){ sm.s.msk[wv][0] = (unsigned int)bm; sm.s.msk[wv][1] = (unsigned int)(bm >> 32); }
      __syncthreads();
      unsigned long long M0 = sm.s.msk[0][0] | ((unsigned long long)sm.s.msk[0][1] << 32);
      unsigned long long M1 = sm.s.msk[1][0] | ((unsigned long long)sm.s.msk[1][1] << 32);
      unsigned long long M2 = sm.s.msk[2][0] | ((unsigned long long)sm.s.msk[2][1] << 32);
      unsigned long long M3 = sm.s.msk[3][0] | ((unsigned long long)sm.s.msk[3][1] << 32);
      float a0 = 0.f, a1 = 0.f, a2 = 0.f, a3 = 0.f;
#pragma unroll 1
      for (int c = 0; c < 64; ++c){
        int r0a = (int)((M0 >> c) & 1), r1a = (int)((M1 >> c) & 1);
        int r2a = (int)((M2 >> c) & 1), r3a = (int)((M3 >> c) & 1);
        if (r0a | r1a | r2a | r3a){
          int k = c * 4;
          float g0 = ldin(P.gmat, (size_t)(k+0)*256 + t, isbf);
          float g1 = ldin(P.gmat, (size_t)(k+1)*256 + t, isbf);
          float g2 = ldin(P.gmat, (size_t)(k+2)*256 + t, isbf);
          float g3 = ldin(P.gmat, (size_t)(k+3)*256 + t, isbf);
          if (r0a){ float4 tv = *(float4*)&sm.s.tabs[0][k]; a0 += tv.x*g0 + tv.y*g1 + tv.z*g2 + tv.w*g3; }
          if (r1a){ float4 tv = *(float4*)&sm.s.tabs[1][k]; a1 += tv.x*g0 + tv.y*g1 + tv.z*g2 + tv.w*g3; }
          if (r2a){ float4 tv = *(float4*)&sm.s.tabs[2][k]; a2 += tv.x*g0 + tv.y*g1 + tv.z*g2 + tv.w*g3; }
          if (r3a){ float4 tv = *(float4*)&sm.s.tabs[3][k]; a3 += tv.x*g0 + tv.y*g1 + tv.z*g2 + tv.w*g3; }
        }
      }
      xm[(size_t)(b0+0)*256 + t] = a0 * xn[(size_t)(b0+0)*256 + t];
      xm[(size_t)(b0+1)*256 + t] = a1 * xn[(size_t)(b0+1)*256 + t];
      xm[(size_t)(b0+2)*256 + t] = a2 * xn[(size_t)(b0+2)*256 + t];
      xm[(size_t)(b0+3)*256 + t] = a3 * xn[(size_t)(b0+3)*256 + t];
    }
    gbar(bar);

    // ---- D: self-attention + amap (4 batch rows per block) -----------------
    {
      float w0 = ldin(P.siw, s*3+0, isbf), w1 = ldin(P.siw, s*3+1, isbf), w2 = ldin(P.siw, s*3+2, isbf);
      float b0 = ldin(P.sib, s*3+0, isbf), b1 = ldin(P.sib, s*3+1, isbf), b2 = ldin(P.sib, s*3+2, isbf);
      float ow = ldin(P.sow, s, isbf), ob = ldin(P.sob, s, isbf);
      for (int it = 0; it < 4; ++it){
        int b = it * 256 + bid;
        float xv = xm[(size_t)b*256 + t];
        float q = xv*w0 + b0, k = xv*w1 + b1, v = xv*w2 + b2;
        sm.a.qs[t] = q; sm.a.ks[t] = k; sm.a.vs[t] = v;
        int lane = t & 63, wv = t >> 6;
        float km = wmaxr(k), kn = wminr(k);
        if (lane == 0){ sm.a.r1[wv] = km; sm.a.r2[wv] = kn; }
        __syncthreads();
        float kmax = fmaxf(fmaxf(sm.a.r1[0], sm.a.r1[1]), fmaxf(sm.a.r1[2], sm.a.r1[3]));
        float kmin = fminf(fminf(sm.a.r2[0], sm.a.r2[1]), fminf(sm.a.r2[2], sm.a.r2[3]));
        float mi = (q >= 0.f) ? q*kmax : q*kmin;
        float Z = 0.f, Y = 0.f;
#pragma unroll 8
        for (int j = 0; j < 256; j += 4){
          float4 k4 = *(const float4*)&sm.a.ks[j];
          float4 v4 = *(const float4*)&sm.a.vs[j];
          float e0 = __expf(q*k4.x - mi), e1 = __expf(q*k4.y - mi);
          float e2 = __expf(q*k4.z - mi), e3 = __expf(q*k4.w - mi);
          Z += (e0 + e1) + (e2 + e3);
          Y += (e0*v4.x + e1*v4.y) + (e2*v4.z + e3*v4.w);
        }
        float rzv = 1.f / Z;
        y[(size_t)b*256 + t] = Y*rzv*ow + ob;
        sm.a.ms[t] = mi; sm.a.rz[t] = rzv;
        __syncthreads();
        int c0 = (t & 127) * 2;
        int rh = (t >> 7) * 128;
        float k0 = sm.a.ks[c0], k1 = sm.a.ks[c0 + 1];
        size_t base = ((size_t)s*BATCH + b) * 65536 + c0;
#pragma unroll 8
        for (int i = 0; i < 128; i += 4){
          int r = rh + i;
          float4 q4 = *(const float4*)&sm.a.qs[r];
          float4 m4 = *(const float4*)&sm.a.ms[r];
          float4 s4 = *(const float4*)&sm.a.rz[r];
          float e00 = __expf(q4.x*k0 - m4.x) * s4.x, e01 = __expf(q4.x*k1 - m4.x) * s4.x;
          float e10 = __expf(q4.y*k0 - m4.y) * s4.y, e11 = __expf(q4.y*k1 - m4.y) * s4.y;
          float e20 = __expf(q4.z*k0 - m4.z) * s4.z, e21 = __expf(q4.z*k1 - m4.z) * s4.z;
          float e30 = __expf(q4.w*k0 - m4.w) * s4.w, e31 = __expf(q4.w*k1 - m4.w) * s4.w;
          *(float2*)(amaps + base + (size_t)(r+0)*256) = make_float2(e00, e01);
          *(float2*)(amaps + base + (size_t)(r+1)*256) = make_float2(e10, e11);
          *(float2*)(amaps + base + (size_t)(r+2)*256) = make_float2(e20, e21);
          *(float2*)(amaps + base + (size_t)(r+3)*256) = make_float2(e30, e31);
        }
        __syncthreads();
      }
    }
    gbar(bar);

    // ---- E: step GEMM K=512 on [y | bemv] -> H1 ----------------------------
    {
      const int n0 = (bid & 7) * 32, m0 = (bid >> 3) * 32;
      auto lda = [&](int k0, int lr, int lk) -> float4 {
        int gk = k0 + lk, gr = m0 + lr;
        if (gk < 256) return *(const float4*)(y + (size_t)gr*256 + gk);
        return ld4(P.bemv, (size_t)gr*256 + (gk - 256), isbf);
      };
      auto ldw = [&](int k0, int lr, int lk) -> float4 {
        return ld4(P.sfc0, (size_t)s*131072 + (size_t)(n0 + lr)*512 + k0 + lk, isbf);
      };
      gemm_body(lda, ldw, 16, sm.g, t, n0, m0, H1);
    }
    gbar(bar);

    // ---- F: gstats on H1 ---------------------------------------------------
    if (bid < 64) gstats_body(sm.t, H1, P.sbnw0, P.sbnb0, (size_t)s*256, sa0, sb0, isbf, bid, t);
    gbar(bar);

    // ---- G: GLU-fused GEMM K=128 -> H2 -------------------------------------
    {
      const int n0 = (bid & 7) * 32, m0 = (bid >> 3) * 32;
      auto lda = [&](int k0, int lr, int lk) -> float4 {
        int gk = k0 + lk, gr = m0 + lr, g = gr >> 7;
        const float* h = H1 + (size_t)gr*256;
        float4 h0 = *(const float4*)(h + gk);
        float4 h1 = *(const float4*)(h + gk + 128);
        float4 A0 = *(const float4*)(sa0 + g*256 + gk);
        float4 B0 = *(const float4*)(sb0 + g*256 + gk);
        float4 A1 = *(const float4*)(sa0 + g*256 + gk + 128);
        float4 B1 = *(const float4*)(sb0 + g*256 + gk + 128);
        float4 r;
        r.x = (h0.x*A0.x+B0.x) / (1.f + __expf(-(h1.x*A1.x+B1.x)));
        r.y = (h0.y*A0.y+B0.y) / (1.f + __expf(-(h1.y*A1.y+B1.y)));
        r.z = (h0.z*A0.z+B0.z) / (1.f + __expf(-(h1.z*A1.z+B1.z)));
        r.w = (h0.w*A0.w+B0.w) / (1.f + __expf(-(h1.w*A1.w+B1.w)));
        return r;
      };
      auto ldw = [&](int k0, int lr, int lk) -> float4 {
        return ld4(P.sfc1, (size_t)s*32768 + (size_t)(n0 + lr)*128 + k0 + lk, isbf);
      };
      gemm_body(lda, ldw, 4, sm.g, t, n0, m0, H2);
    }
    gbar(bar);

    // ---- H: gstats on H2 ---------------------------------------------------
    if (bid < 64) gstats_body(sm.t, H2, P.sbnw1, P.sbnb1, (size_t)s*256, sa1, sb1, isbf, bid, t);
    gbar(bar);
  }

  // ---- final: steps_out[2] + m_loss ----------------------------------------
  {
    int idx = bid * 256 + t;
    int r = idx >> 6, j = idx & 63;
    float f = combine_scalar(H1, H2, sa0, sb0, sa1, sb1, r, j);
    P.out[(size_t)2*65536 + idx] = f > 0.f ? f : 0.01f*f;
  }
  if (bid == 0){
    float ssum = 0.f;
    for (int i = t; i < N_STEPS*BATCH; i += 256) ssum += lrow[i];
    ssum = block_sum(ssum, sm.r.sb);
    if (t == 0) P.out[196608] = ssum * (1.f/(N_STEPS*(float)BATCH));
  }
}

extern "C" void kernel_launch(void* const* d_in, const int* in_sizes, int n_in,
                              void* d_out, int out_size, void* d_ws, size_t ws_size,
                              hipStream_t stream){
  KParams P;
  P.x     = d_in[0];  P.bemv  = d_in[1];  P.gmat  = d_in[2];
  P.bn_w  = d_in[3];  P.bn_b  = d_in[4];
  P.ifc0  = d_in[5];  P.ibnw0 = d_in[6];  P.ibnb0 = d_in[7];
  P.ifc1  = d_in[8];  P.ibnw1 = d_in[9];  P.ibnb1 = d_in[10];
  P.sfc0  = d_in[11]; P.sbnw0 = d_in[12]; P.sbnb0 = d_in[13];
  P.sfc1  = d_in[14]; P.sbnw1 = d_in[15]; P.sbnb1 = d_in[16];
  P.afc   = d_in[17]; P.abnw  = d_in[18]; P.abnb  = d_in[19];
  P.siw   = d_in[20]; P.sib   = d_in[21]; P.sow   = d_in[22]; P.sob = d_in[23];
  P.out   = (float*)d_out;
  P.ws    = (float*)d_ws;
  initbar_k<<<1, 1, 0, stream>>>(P.ws);
  mega_k<<<NBLK, 256, 0, stream>>>(P);
}

// Round 9
// 442.975 us; speedup vs baseline: 2.5361x; 2.5361x over previous
//
#include <hip/hip_runtime.h>
#include <hip/hip_bf16.h>

#define BATCH 1024
#define N_STEPS 3
#define GAMMA_C 1.3f
#define BN_EPS_C 1e-5f
#define SQRT_HALF_C 0.70710678118654752440f
#define ST_STRIDE 786432   // 3*1024*256 per state array

// ---- input loader: f32 or bf16 decided at runtime by detector flag --------
__device__ __forceinline__ float ldin(const void* p, size_t i, int isbf){
  if (isbf) return __bfloat162float(((const __hip_bfloat16*)p)[i]);
  return ((const float*)p)[i];
}
__device__ __forceinline__ float4 ld4(const void* p, size_t i, int isbf){
  if (!isbf) return *(const float4*)((const float*)p + i);
  const __hip_bfloat16* q = (const __hip_bfloat16*)p + i;
  return make_float4(__bfloat162float(q[0]), __bfloat162float(q[1]),
                     __bfloat162float(q[2]), __bfloat162float(q[3]));
}

// ---- wave (64-lane) butterfly reductions ----------------------------------
__device__ __forceinline__ float wsum(float v){
#pragma unroll
  for (int o = 32; o > 0; o >>= 1) v += __shfl_xor(v, o);
  return v;
}
__device__ __forceinline__ float wmaxr(float v){
#pragma unroll
  for (int o = 32; o > 0; o >>= 1) v = fmaxf(v, __shfl_xor(v, o));
  return v;
}
__device__ __forceinline__ float wminr(float v){
#pragma unroll
  for (int o = 32; o > 0; o >>= 1) v = fminf(v, __shfl_xor(v, o));
  return v;
}
__device__ __forceinline__ float block_sum(float v, float* sb){
  int t = threadIdx.x;
  sb[t] = v; __syncthreads();
#pragma unroll
  for (int s = 128; s > 0; s >>= 1){
    if (t < s) sb[t] += sb[t + s];
    __syncthreads();
  }
  float r = sb[0]; __syncthreads();
  return r;
}

// ---- amap drain: one block writes one (step, batch-row) amap tile ---------
// state layout: q | k | m | rz, each ST_STRIDE floats, indexed (s*1024+b)*256+i
__device__ __forceinline__ void drain_rows(const float* __restrict__ st,
                                           float* __restrict__ amap,
                                           int s, int b, int t){
  __shared__ __align__(16) float sh[768];
  const float* qS = st;
  const float* kS = st + ST_STRIDE;
  const float* mS = st + 2*ST_STRIDE;
  const float* rS = st + 3*ST_STRIDE;
  size_t sb = ((size_t)s*BATCH + b)*256;
  sh[t]       = qS[sb + t];
  sh[256 + t] = mS[sb + t];
  sh[512 + t] = rS[sb + t];
  __syncthreads();
  int c0 = (t & 127)*2, rh = (t >> 7)*128;
  float k0 = kS[sb + c0], k1 = kS[sb + c0 + 1];
  size_t base = ((size_t)s*BATCH + b)*65536 + c0;
#pragma unroll 8
  for (int i = 0; i < 128; i += 4){
    int r = rh + i;
    float4 q4 = *(const float4*)&sh[r];
    float4 m4 = *(const float4*)&sh[256 + r];
    float4 s4 = *(const float4*)&sh[512 + r];
    float e00 = __expf(q4.x*k0 - m4.x) * s4.x, e01 = __expf(q4.x*k1 - m4.x) * s4.x;
    float e10 = __expf(q4.y*k0 - m4.y) * s4.y, e11 = __expf(q4.y*k1 - m4.y) * s4.y;
    float e20 = __expf(q4.z*k0 - m4.z) * s4.z, e21 = __expf(q4.z*k1 - m4.z) * s4.z;
    float e30 = __expf(q4.w*k0 - m4.w) * s4.w, e31 = __expf(q4.w*k1 - m4.w) * s4.w;
    *(float2*)(amap + base + (size_t)(r+0)*256) = make_float2(e00, e01);
    *(float2*)(amap + base + (size_t)(r+1)*256) = make_float2(e10, e11);
    *(float2*)(amap + base + (size_t)(r+2)*256) = make_float2(e20, e21);
    *(float2*)(amap + base + (size_t)(r+3)*256) = make_float2(e30, e31);
  }
}

// ---- dtype detector --------------------------------------------------------
__global__ void detect_k(const unsigned short* __restrict__ u, float* __restrict__ flag){
  __shared__ int cnt;
  if (threadIdx.x == 0) cnt = 0;
  __syncthreads();
  int c = 0;
  for (int j = 0; j < 16; ++j){
    unsigned short v = u[(size_t)(threadIdx.x * 16 + j) * 2];
    int e = (v >> 7) & 0xFF;
    if (e >= 118 && e <= 134) c++;
  }
  atomicAdd(&cnt, c);
  __syncthreads();
  if (threadIdx.x == 0) flag[0] = (cnt > 2048) ? 1.0f : 0.0f;
}

// ---- full-batch BN stats ---------------------------------------------------
__global__ void bnstats_k(const void* __restrict__ x, float* __restrict__ mean,
                          float* __restrict__ istd, const float* __restrict__ flg){
  __shared__ float sb[256];
  const int isbf = flg[0] != 0.0f;
  int f = blockIdx.x, t = threadIdx.x;
  float s = 0.f, ss = 0.f;
  for (int r = t; r < BATCH; r += 256){
    float v = ldin(x, (size_t)r * 256 + f, isbf);
    s += v; ss += v * v;
  }
  s  = block_sum(s, sb);
  ss = block_sum(ss, sb);
  if (t == 0){
    float m = s * (1.f / BATCH);
    mean[f] = m;
    istd[f] = rsqrtf(ss * (1.f / BATCH) - m * m + BN_EPS_C);
  }
}

__global__ void xn_k(const void* __restrict__ x, const float* __restrict__ mean,
                     const float* __restrict__ istd, const void* __restrict__ bw,
                     const void* __restrict__ bb, float* __restrict__ xn,
                     const float* __restrict__ flg){
  const int isbf = flg[0] != 0.0f;
  int idx = blockIdx.x * 256 + threadIdx.x;
  int f = idx & 255;
  xn[idx] = (ldin(x, idx, isbf) - mean[f]) * istd[f] * ldin(bw, f, isbf) + ldin(bb, f, isbf);
}

// ---- GEMM (BT): C(1024x256) = [A1|A2](1024xK) @ W^T, 1D grid, +drain ------
__global__ __launch_bounds__(256)
void gemm_bt_k(const float* __restrict__ A1, const void* __restrict__ A2, int split,
               const void* __restrict__ W, size_t woff, float* __restrict__ C, int K,
               const float* __restrict__ st, float* __restrict__ amap, int dS, int dR0,
               const float* __restrict__ flg){
  int bid = blockIdx.x, t = threadIdx.x;
  if (bid >= 256){ drain_rows(st, amap, dS, dR0 + bid - 256, t); return; }
  __shared__ float As[32][34];
  __shared__ float Ws[32][34];
  const int isbf = flg[0] != 0.0f;
  const int n0 = (bid & 7) * 32, m0 = (bid >> 3) * 32;
  const int tx = t & 15, ty = t >> 4;
  const int lr = t >> 3, lk = (t & 7) * 4;
  const int nc = K >> 5;
  float a00 = 0.f, a01 = 0.f, a10 = 0.f, a11 = 0.f;

  auto lda = [&](int k0) -> float4 {
    int gk = k0 + lk, gr = m0 + lr;
    if (gk < split) return *(const float4*)(A1 + (size_t)gr * split + gk);
    return ld4(A2, (size_t)gr * (K - split) + (gk - split), isbf);
  };
  auto ldw = [&](int k0) -> float4 {
    return ld4(W, woff + (size_t)(n0 + lr) * K + k0 + lk, isbf);
  };

  float4 ra = lda(0), rw = ldw(0);
  for (int c = 0; c < nc; ++c){
    As[lk+0][lr] = ra.x; As[lk+1][lr] = ra.y; As[lk+2][lr] = ra.z; As[lk+3][lr] = ra.w;
    Ws[lk+0][lr] = rw.x; Ws[lk+1][lr] = rw.y; Ws[lk+2][lr] = rw.z; Ws[lk+3][lr] = rw.w;
    __syncthreads();
    float4 na = ra, nw = rw;
    if (c + 1 < nc){ na = lda((c+1) << 5); nw = ldw((c+1) << 5); }
#pragma unroll
    for (int kk = 0; kk < 32; ++kk){
      float2 av = *(const float2*)&As[kk][ty*2];
      float2 wv = *(const float2*)&Ws[kk][tx*2];
      a00 += av.x * wv.x; a01 += av.x * wv.y;
      a10 += av.y * wv.x; a11 += av.y * wv.y;
    }
    __syncthreads();
    ra = na; rw = nw;
  }
  int r0 = m0 + ty*2, c0 = n0 + tx*2;
  float* Cp = C + (size_t)r0 * 256 + c0;
  Cp[0] = a00; Cp[1] = a01; Cp[256] = a10; Cp[257] = a11;
}

// ---- merged group-stats + GLU-fused GEMM K=128 -> H2, +drain --------------
__global__ __launch_bounds__(256)
void glugemm_k(const float* __restrict__ H1, const void* __restrict__ gw,
               const void* __restrict__ gb, size_t goff,
               const void* __restrict__ W, size_t woff, float* __restrict__ C,
               const float* __restrict__ st, float* __restrict__ amap, int dS, int dR0,
               const float* __restrict__ flg){
  int bid = blockIdx.x, t = threadIdx.x;
  if (bid >= 256){ drain_rows(st, amap, dS, dR0 + bid - 256, t); return; }
  __shared__ __align__(16) float sA[256], sB[256];
  __shared__ float As[32][34];
  __shared__ float Ws[32][34];
  const int isbf = flg[0] != 0.0f;
  const int n0 = (bid & 7) * 32, m0 = (bid >> 3) * 32;
  const int g = bid >> 5;
  {
    const float* Hp = H1 + (size_t)g*32768 + t;
    float s = 0.f, ss = 0.f;
#pragma unroll 8
    for (int i = 0; i < 128; ++i){ float v = Hp[(size_t)i*256]; s += v; ss += v*v; }
    float m = s * (1.f/128), is = rsqrtf(ss * (1.f/128) - m*m + BN_EPS_C);
    float wv = ldin(gw, goff + t, isbf), bv = ldin(gb, goff + t, isbf);
    float A = is * wv;
    sA[t] = A; sB[t] = bv - m*A;
  }
  __syncthreads();
  const int tx = t & 15, ty = t >> 4;
  const int lr = t >> 3, lk = (t & 7) * 4;
  float a00 = 0.f, a01 = 0.f, a10 = 0.f, a11 = 0.f;

  auto lda = [&](int k0) -> float4 {
    int gk = k0 + lk, gr = m0 + lr;
    const float* h = H1 + (size_t)gr*256;
    float4 h0 = *(const float4*)(h + gk);
    float4 h1 = *(const float4*)(h + gk + 128);
    float4 A0 = *(const float4*)(sA + gk);
    float4 B0 = *(const float4*)(sB + gk);
    float4 A1 = *(const float4*)(sA + gk + 128);
    float4 B1 = *(const float4*)(sB + gk + 128);
    float4 r;
    r.x = (h0.x*A0.x+B0.x) / (1.f + __expf(-(h1.x*A1.x+B1.x)));
    r.y = (h0.y*A0.y+B0.y) / (1.f + __expf(-(h1.y*A1.y+B1.y)));
    r.z = (h0.z*A0.z+B0.z) / (1.f + __expf(-(h1.z*A1.z+B1.z)));
    r.w = (h0.w*A0.w+B0.w) / (1.f + __expf(-(h1.w*A1.w+B1.w)));
    return r;
  };
  auto ldw = [&](int k0) -> float4 {
    return ld4(W, woff + (size_t)(n0 + lr) * 128 + k0 + lk, isbf);
  };

  float4 ra = lda(0), rw = ldw(0);
#pragma unroll 1
  for (int c = 0; c < 4; ++c){
    As[lk+0][lr] = ra.x; As[lk+1][lr] = ra.y; As[lk+2][lr] = ra.z; As[lk+3][lr] = ra.w;
    Ws[lk+0][lr] = rw.x; Ws[lk+1][lr] = rw.y; Ws[lk+2][lr] = rw.z; Ws[lk+3][lr] = rw.w;
    __syncthreads();
    float4 na = ra, nw = rw;
    if (c + 1 < 4){ na = lda((c+1) << 5); nw = ldw((c+1) << 5); }
#pragma unroll
    for (int kk = 0; kk < 32; ++kk){
      float2 av = *(const float2*)&As[kk][ty*2];
      float2 wv = *(const float2*)&Ws[kk][tx*2];
      a00 += av.x * wv.x; a01 += av.x * wv.y;
      a10 += av.y * wv.x; a11 += av.y * wv.y;
    }
    __syncthreads();
    ra = na; rw = nw;
  }
  int r0 = m0 + ty*2, c0 = n0 + tx*2;
  float* Cp = C + (size_t)r0 * 256 + c0;
  Cp[0] = a00; Cp[1] = a01; Cp[256] = a10; Cp[257] = a11;
}

// ---- merged group-stats + sparsemax + prior + loss + sparse xm, +drain ----
__global__ __launch_bounds__(256)
void spmax_k(const float* __restrict__ Ha, const void* __restrict__ gw,
             const void* __restrict__ gb, size_t goff, float* __restrict__ prior,
             const float* __restrict__ xn, const void* __restrict__ gmat,
             float* __restrict__ xm, float* __restrict__ lrow, int first,
             const float* __restrict__ st, float* __restrict__ amap, int dS, int dR0,
             const float* __restrict__ flg){
  int bid = blockIdx.x, t = threadIdx.x;
  if (bid >= 256){ drain_rows(st, amap, dS, dR0 + bid - 256, t); return; }
  __shared__ __align__(16) float sAA[256], sBA[256];
  __shared__ __align__(16) float tabs[4][256];
  __shared__ unsigned int msk[4][2];
  const int isbf = flg[0] != 0.0f;
  const int g = bid >> 5;
  {
    const float* Hp = Ha + (size_t)g*32768 + t;
    float s = 0.f, ss = 0.f;
#pragma unroll 8
    for (int i = 0; i < 128; ++i){ float v = Hp[(size_t)i*256]; s += v; ss += v*v; }
    float m = s * (1.f/128), is = rsqrtf(ss * (1.f/128) - m*m + BN_EPS_C);
    float wv = ldin(gw, goff + t, isbf), bv = ldin(gb, goff + t, isbf);
    float A = is * wv;
    sAA[t] = A; sBA[t] = bv - m*A;
  }
  __syncthreads();
  int lane = t & 63, wv = t >> 6;
  int b0 = bid * 4;
  int b = b0 + wv;
  size_t rb = (size_t)b * 256;
  int j0 = lane * 4;
  float4 h4 = *(const float4*)(Ha + rb + j0);
  float4 A4 = *(const float4*)(sAA + j0);
  float4 B4 = *(const float4*)(sBA + j0);
  float pr[4];
  if (first){ pr[0] = pr[1] = pr[2] = pr[3] = 1.f; }
  else { float4 p4 = *(const float4*)(prior + rb + j0); pr[0]=p4.x; pr[1]=p4.y; pr[2]=p4.z; pr[3]=p4.w; }
  float z[4];
  z[0] = (h4.x*A4.x + B4.x) * pr[0];
  z[1] = (h4.y*A4.y + B4.y) * pr[1];
  z[2] = (h4.z*A4.z + B4.z) * pr[2];
  z[3] = (h4.w*A4.w + B4.w) * pr[3];
  float zm = wmaxr(fmaxf(fmaxf(z[0], z[1]), fmaxf(z[2], z[3])));
  float lo = zm - 1.f, hi = zm;
#pragma unroll 1
  for (int it = 0; it < 30; ++it){
    float mid = 0.5f * (lo + hi);
    float sv = 0.f;
#pragma unroll
    for (int e = 0; e < 4; ++e){ float d = z[e] - mid; sv += d > 0.f ? d : 0.f; }
    sv = wsum(sv);
    if (sv >= 1.f) lo = mid; else hi = mid;
  }
  float tau = 0.5f * (lo + hi);
  float p[4], ls = 0.f;
#pragma unroll
  for (int e = 0; e < 4; ++e){
    p[e] = z[e] - tau; p[e] = p[e] > 0.f ? p[e] : 0.f;
    ls += p[e] * __logf(p[e] + 1e-15f);
  }
  *(float4*)&tabs[wv][j0] = make_float4(p[0], p[1], p[2], p[3]);
  *(float4*)(prior + rb + j0) = make_float4(pr[0]*(GAMMA_C-p[0]), pr[1]*(GAMMA_C-p[1]),
                                            pr[2]*(GAMMA_C-p[2]), pr[3]*(GAMMA_C-p[3]));
  ls = wsum(ls);
  if (lane == 0) lrow[b] = ls;
  bool nz = (p[0] > 0.f) | (p[1] > 0.f) | (p[2] > 0.f) | (p[3] > 0.f);
  unsigned long long bm = __ballot(nz);
  if (lane == 0){ msk[wv][0] = (unsigned int)bm; msk[wv][1] = (unsigned int)(bm >> 32); }
  __syncthreads();
  unsigned long long M0 = msk[0][0] | ((unsigned long long)msk[0][1] << 32);
  unsigned long long M1 = msk[1][0] | ((unsigned long long)msk[1][1] << 32);
  unsigned long long M2 = msk[2][0] | ((unsigned long long)msk[2][1] << 32);
  unsigned long long M3 = msk[3][0] | ((unsigned long long)msk[3][1] << 32);
  float a0 = 0.f, a1 = 0.f, a2 = 0.f, a3 = 0.f;
#pragma unroll 1
  for (int c = 0; c < 64; ++c){
    int r0a = (int)((M0 >> c) & 1), r1a = (int)((M1 >> c) & 1);
    int r2a = (int)((M2 >> c) & 1), r3a = (int)((M3 >> c) & 1);
    if (r0a | r1a | r2a | r3a){
      int k = c * 4;
      float g0 = ldin(gmat, (size_t)(k+0)*256 + t, isbf);
      float g1 = ldin(gmat, (size_t)(k+1)*256 + t, isbf);
      float g2 = ldin(gmat, (size_t)(k+2)*256 + t, isbf);
      float g3 = ldin(gmat, (size_t)(k+3)*256 + t, isbf);
      if (r0a){ float4 tv = *(float4*)&tabs[0][k]; a0 += tv.x*g0 + tv.y*g1 + tv.z*g2 + tv.w*g3; }
      if (r1a){ float4 tv = *(float4*)&tabs[1][k]; a1 += tv.x*g0 + tv.y*g1 + tv.z*g2 + tv.w*g3; }
      if (r2a){ float4 tv = *(float4*)&tabs[2][k]; a2 += tv.x*g0 + tv.y*g1 + tv.z*g2 + tv.w*g3; }
      if (r3a){ float4 tv = *(float4*)&tabs[3][k]; a3 += tv.x*g0 + tv.y*g1 + tv.z*g2 + tv.w*g3; }
    }
  }
  xm[(size_t)(b0+0)*256 + t] = a0 * xn[(size_t)(b0+0)*256 + t];
  xm[(size_t)(b0+1)*256 + t] = a1 * xn[(size_t)(b0+1)*256 + t];
  xm[(size_t)(b0+2)*256 + t] = a2 * xn[(size_t)(b0+2)*256 + t];
  xm[(size_t)(b0+3)*256 + t] = a3 * xn[(size_t)(b0+3)*256 + t];
}

// ---- attention pass A: y + softmax state (q,k,m,rz), +drain ---------------
__global__ __launch_bounds__(256)
void attnA_k(const float* __restrict__ xm, float* __restrict__ y,
             const void* __restrict__ siw, const void* __restrict__ sib,
             const void* __restrict__ sow, const void* __restrict__ sob,
             int s, float* __restrict__ st, float* __restrict__ amap, int dS, int dR0,
             const float* __restrict__ flg){
  int bid = blockIdx.x, t = threadIdx.x;
  if (bid >= 1024){ drain_rows(st, amap, dS, dR0 + bid - 1024, t); return; }
  __shared__ __align__(16) float ks[256], vs[256];
  __shared__ float r1[4], r2[4];
  const int isbf = flg[0] != 0.0f;
  int b = bid;
  float w0 = ldin(siw, s*3+0, isbf), w1 = ldin(siw, s*3+1, isbf), w2 = ldin(siw, s*3+2, isbf);
  float b0 = ldin(sib, s*3+0, isbf), b1 = ldin(sib, s*3+1, isbf), b2 = ldin(sib, s*3+2, isbf);
  float ow = ldin(sow, s, isbf), ob = ldin(sob, s, isbf);
  float xv = xm[(size_t)b*256 + t];
  float q = xv*w0 + b0, k = xv*w1 + b1, v = xv*w2 + b2;
  ks[t] = k; vs[t] = v;
  int lane = t & 63, wv = t >> 6;
  float km = wmaxr(k), kn = wminr(k);
  if (lane == 0){ r1[wv] = km; r2[wv] = kn; }
  __syncthreads();
  float kmax = fmaxf(fmaxf(r1[0], r1[1]), fmaxf(r1[2], r1[3]));
  float kmin = fminf(fminf(r2[0], r2[1]), fminf(r2[2], r2[3]));
  float mi = (q >= 0.f) ? q*kmax : q*kmin;
  float Z = 0.f, Y = 0.f;
#pragma unroll 8
  for (int j = 0; j < 256; j += 4){
    float4 k4 = *(const float4*)&ks[j];
    float4 v4 = *(const float4*)&vs[j];
    float e0 = __expf(q*k4.x - mi), e1 = __expf(q*k4.y - mi);
    float e2 = __expf(q*k4.z - mi), e3 = __expf(q*k4.w - mi);
    Z += (e0 + e1) + (e2 + e3);
    Y += (e0*v4.x + e1*v4.y) + (e2*v4.z + e3*v4.w);
  }
  float rz = 1.f / Z;
  y[(size_t)b*256 + t] = Y*rz*ow + ob;
  size_t sb = ((size_t)s*BATCH + b)*256 + t;
  st[sb]               = q;
  st[ST_STRIDE + sb]   = k;
  st[2*ST_STRIDE + sb] = mi;
  st[3*ST_STRIDE + sb] = rz;
}

// ---- merged 2x group-stats + combine (att + optional steps_out), +drain ---
__global__ __launch_bounds__(256)
void comb_k(const float* __restrict__ H1, const void* __restrict__ pw0,
            const void* __restrict__ pb0, size_t off0,
            const float* __restrict__ H2, const void* __restrict__ pw1,
            const void* __restrict__ pb1, size_t off1,
            float* __restrict__ att, float* __restrict__ steps,
            const float* __restrict__ st, float* __restrict__ amap, int dS, int dR0,
            const float* __restrict__ flg){
  int bid = blockIdx.x, t = threadIdx.x;
  if (bid >= 512){ drain_rows(st, amap, dS, dR0 + bid - 512, t); return; }
  __shared__ float sA0[256], sB0[256], sA1[256], sB1[256];
  const int isbf = flg[0] != 0.0f;
  const int g = bid >> 6;
  {
    const float* Hp = H1 + (size_t)g*32768 + t;
    float s = 0.f, ss = 0.f;
#pragma unroll 8
    for (int i = 0; i < 128; ++i){ float v = Hp[(size_t)i*256]; s += v; ss += v*v; }
    float m = s * (1.f/128), is = rsqrtf(ss * (1.f/128) - m*m + BN_EPS_C);
    float wv = ldin(pw0, off0 + t, isbf), bv = ldin(pb0, off0 + t, isbf);
    float A = is * wv;
    sA0[t] = A; sB0[t] = bv - m*A;
  }
  {
    const float* Hp = H2 + (size_t)g*32768 + t;
    float s = 0.f, ss = 0.f;
#pragma unroll 8
    for (int i = 0; i < 128; ++i){ float v = Hp[(size_t)i*256]; s += v; ss += v*v; }
    float m = s * (1.f/128), is = rsqrtf(ss * (1.f/128) - m*m + BN_EPS_C);
    float wv = ldin(pw1, off1 + t, isbf), bv = ldin(pb1, off1 + t, isbf);
    float A = is * wv;
    sA1[t] = A; sB1[t] = bv - m*A;
  }
  __syncthreads();
  int r = bid*2 + (t >> 7), j = t & 127;
  float h0 = H1[(size_t)r*256 + j], h1 = H1[(size_t)r*256 + j + 128];
  float u0 = h0 * sA0[j]     + sB0[j];
  float u1 = h1 * sA0[j+128] + sB0[j+128];
  float g0 = u0 / (1.f + __expf(-u1));
  float v0 = H2[(size_t)r*256 + j]     * sA1[j]     + sB1[j];
  float v1 = H2[(size_t)r*256 + j+128] * sA1[j+128] + sB1[j+128];
  float g1 = v0 / (1.f + __expf(-v1));
  float f = (g0 + g1) * SQRT_HALF_C;
  if (j < 64){
    if (steps) steps[(size_t)r*64 + j] = f > 0.f ? f : 0.01f*f;
  } else {
    att[(size_t)r*64 + (j - 64)] = f;
  }
}

// ---- standalone drain ------------------------------------------------------
__global__ __launch_bounds__(256)
void drain_k(const float* __restrict__ st, float* __restrict__ amap, int s, int row0){
  drain_rows(st, amap, s, row0 + blockIdx.x, threadIdx.x);
}

// ---- final m_loss ----------------------------------------------------------
__global__ void mloss_k(const float* __restrict__ lrow, float* __restrict__ outp){
  __shared__ float sb[256];
  int t = threadIdx.x;
  float s = 0.f;
  for (int i = t; i < N_STEPS*BATCH; i += 256) s += lrow[i];
  s = block_sum(s, sb);
  if (t == 0) outp[0] = s * (1.f/(N_STEPS*(float)BATCH));
}

extern "C" void kernel_launch(void* const* d_in, const int* in_sizes, int n_in,
                              void* d_out, int out_size, void* d_ws, size_t ws_size,
                              hipStream_t stream){
  const void* x         = d_in[0];
  const void* bemv      = d_in[1];
  const void* gmat      = d_in[2];
  const void* bn_w      = d_in[3];
  const void* bn_b      = d_in[4];
  const void* init_fc0  = d_in[5];
  const void* init_bnw0 = d_in[6];
  const void* init_bnb0 = d_in[7];
  const void* init_fc1  = d_in[8];
  const void* init_bnw1 = d_in[9];
  const void* init_bnb1 = d_in[10];
  const void* step_fc0  = d_in[11];
  const void* step_bnw0 = d_in[12];
  const void* step_bnb0 = d_in[13];
  const void* step_fc1  = d_in[14];
  const void* step_bnw1 = d_in[15];
  const void* step_bnb1 = d_in[16];
  const void* att_fc    = d_in[17];
  const void* att_bnw   = d_in[18];
  const void* att_bnb   = d_in[19];
  const void* sa_in_w   = d_in[20];
  const void* sa_in_b   = d_in[21];
  const void* sa_out_w  = d_in[22];
  const void* sa_out_b  = d_in[23];

  float* out       = (float*)d_out;
  float* steps_out = out;                               // 3*1024*64
  float* mloss_out = out + 196608;                      // 1
  float* amaps     = out + 196609;                      // 3*1024*256*256

  float* w     = (float*)d_ws;
  float* flag  = w;                   // [0,16)
  float* mean  = w + 16;              // 256
  float* istd  = w + 272;             // 256
  float* lrow  = w + 528;             // 3072
  float* xn    = w + 4096;            // 262144
  float* H1    = xn + 262144;
  float* H2    = H1 + 262144;
  float* att   = H2 + 262144;         // 65536
  float* xm    = att + 65536;         // 262144
  float* prior = xm + 262144;
  float* y     = prior + 262144;
  float* st    = y + 262144;          // 4 * ST_STRIDE = 3145728

  detect_k<<<1, 256, 0, stream>>>((const unsigned short*)x, flag);
  bnstats_k<<<256, 256, 0, stream>>>(x, mean, istd, flag);
  xn_k<<<1024, 256, 0, stream>>>(x, mean, istd, bn_w, bn_b, xn, flag);

  // initial feature transformer on [xn | bemv]
  gemm_bt_k<<<256, 256, 0, stream>>>(xn, bemv, 256, init_fc0, 0, H1, 512, st, amaps, 0, 0, flag);
  glugemm_k<<<256, 256, 0, stream>>>(H1, init_bnw0, init_bnb0, 0, init_fc1, 0, H2, st, amaps, 0, 0, flag);
  comb_k<<<512, 256, 0, stream>>>(H1, init_bnw0, init_bnb0, 0, H2, init_bnw1, init_bnb1, 0,
                                  att, nullptr, st, amaps, 0, 0, flag);

  for (int s = 0; s < N_STEPS; ++s){
    int pd = s - 1;
    int dn = (pd >= 0) ? 160 : 0;
    // A: a-GEMM K=64 on att -> H1 (pre-GBN "Ha")  [drains pd rows 544..704)
    gemm_bt_k<<<256 + dn, 256, 0, stream>>>(att, nullptr, 64, att_fc, (size_t)s*16384, H1, 64,
                                            st, amaps, pd, 544, flag);
    // C: stats + sparsemax + prior + loss + sparse xm  [drains pd rows 704..864)
    spmax_k<<<256 + dn, 256, 0, stream>>>(H1, att_bnw, att_bnb, (size_t)s*256, prior, xn, gmat,
                                          xm, lrow + s*1024, s == 0, st, amaps, pd, 704, flag);
    // D: attention pass A -> y + state  [drains pd rows 864..1024)
    attnA_k<<<1024 + dn, 256, 0, stream>>>(xm, y, sa_in_w, sa_in_b, sa_out_w, sa_out_b, s,
                                           st, amaps, pd, 864, flag);
    // E: step GEMM K=512 on [y|bemv] -> H1  [drains s rows 0..224)
    gemm_bt_k<<<256 + 224, 256, 0, stream>>>(y, bemv, 256, step_fc0, (size_t)s*131072, H1, 512,
                                             st, amaps, s, 0, flag);
    // G: stats + GLU GEMM K=128 -> H2  [drains s rows 224..384)
    glugemm_k<<<256 + 160, 256, 0, stream>>>(H1, step_bnw0, step_bnb0, (size_t)s*256,
                                             step_fc1, (size_t)s*32768, H2, st, amaps, s, 224, flag);
    // comb: stats x2 + combine -> att, steps_out[s]  [drains s rows 384..544)
    comb_k<<<512 + 160, 256, 0, stream>>>(H1, step_bnw0, step_bnb0, (size_t)s*256,
                                          H2, step_bnw1, step_bnb1, (size_t)s*256,
                                          att, steps_out + (size_t)s*65536, st, amaps, s, 384, flag);
  }
  // leftover amap rows for step 2
  drain_k<<<480, 256, 0, stream>>>(st, amaps, 2, 544);
  mloss_k<<<1, 256, 0, stream>>>(lrow, mloss_out);
}